// Round 1
// baseline (3346.059 us; speedup 1.0000x reference)
//
#include <hip/hip_runtime.h>
#include <math.h>

// Problem constants (from reference)
#define BATCH 32
#define TSEQ  2048
#define NF    512          // feature dim N
#define HDIM  1024
#define ODIM  512
#define MROWS (BATCH*TSEQ) // 65536 flattened rows

// ---------------------------------------------------------------------------
// Small scalar precompute: softmax(cheb_weights) and sigmoid(alpha) -> scal[4]
// ---------------------------------------------------------------------------
__global__ void scal_kernel(const float* __restrict__ cheb,
                            const float* __restrict__ alpha,
                            float* __restrict__ scal)
{
    if (threadIdx.x == 0 && blockIdx.x == 0) {
        float c0 = cheb[0], c1 = cheb[1], c2 = cheb[2];
        float m  = fmaxf(c0, fmaxf(c1, c2));
        float e0 = expf(c0 - m), e1 = expf(c1 - m), e2 = expf(c2 - m);
        float s  = e0 + e1 + e2;
        scal[0] = e0 / s; scal[1] = e1 / s; scal[2] = e2 / s;
        scal[3] = 1.f / (1.f + expf(-alpha[0]));
    }
}

// ---------------------------------------------------------------------------
// Row LayerNorm over width W (optionally followed by exact GeLU).
// block = W/4 threads, one block per row, float4 loads.
// ---------------------------------------------------------------------------
template<int W, bool GELU>
__global__ __launch_bounds__(W/4)
void row_ln(const float* __restrict__ in, float* __restrict__ out,
            const float* __restrict__ g, const float* __restrict__ bb)
{
    constexpr int NT = W / 4;
    constexpr int NW = NT / 64;
    __shared__ float ssum[NW], ssq[NW];

    const long row = blockIdx.x;
    const int tid  = threadIdx.x;

    float4 v = *(const float4*)&in[row * (long)W + tid * 4];
    float s = v.x + v.y + v.z + v.w;
    float q = v.x*v.x + v.y*v.y + v.z*v.z + v.w*v.w;

    #pragma unroll
    for (int off = 32; off > 0; off >>= 1) {
        s += __shfl_down(s, off);
        q += __shfl_down(q, off);
    }
    if ((tid & 63) == 0) { ssum[tid >> 6] = s; ssq[tid >> 6] = q; }
    __syncthreads();
    float st = 0.f, qt = 0.f;
    #pragma unroll
    for (int i = 0; i < NW; i++) { st += ssum[i]; qt += ssq[i]; }

    const float mean = st * (1.f / W);
    const float var  = qt * (1.f / W) - mean * mean;
    const float rstd = rsqrtf(var + 1e-5f);

    float4 gv = *(const float4*)&g[tid * 4];
    float4 bv = *(const float4*)&bb[tid * 4];

    float4 o;
    o.x = (v.x - mean) * rstd * gv.x + bv.x;
    o.y = (v.y - mean) * rstd * gv.y + bv.y;
    o.z = (v.z - mean) * rstd * gv.z + bv.z;
    o.w = (v.w - mean) * rstd * gv.w + bv.w;
    if (GELU) {
        o.x = 0.5f * o.x * (1.f + erff(o.x * 0.70710678118f));
        o.y = 0.5f * o.y * (1.f + erff(o.y * 0.70710678118f));
        o.z = 0.5f * o.z * (1.f + erff(o.z * 0.70710678118f));
        o.w = 0.5f * o.w * (1.f + erff(o.w * 0.70710678118f));
    }
    *(float4*)&out[row * (long)W + tid * 4] = o;
}

// ---------------------------------------------------------------------------
// Per-(b,n) time stats on xln: mu[b,n] = mean_t, invn[b,n] = 1/max(||x-mu||,EPS)
// grid (NF/64, BATCH), block 256 = 64 cols x 4 t-groups
// ---------------------------------------------------------------------------
__global__ __launch_bounds__(256)
void colstats(const float* __restrict__ xln,
              float* __restrict__ mu, float* __restrict__ invn)
{
    const int b    = blockIdx.y;
    const int lane = threadIdx.x & 63;
    const int n    = blockIdx.x * 64 + lane;
    const int tp   = threadIdx.x >> 6;

    const float* base = xln + (long)b * TSEQ * NF + n;
    float s = 0.f, q = 0.f;
    for (int t = tp; t < TSEQ; t += 4) {
        float v = base[(long)t * NF];
        s += v; q += v * v;
    }
    __shared__ float ss[4][64], sq[4][64];
    ss[tp][lane] = s; sq[tp][lane] = q;
    __syncthreads();
    if (tp == 0) {
        s = ss[0][lane] + ss[1][lane] + ss[2][lane] + ss[3][lane];
        q = sq[0][lane] + sq[1][lane] + sq[2][lane] + sq[3][lane];
        float m    = s * (1.f / TSEQ);
        float nrm2 = fmaxf(q - (float)TSEQ * m * m, 0.f);
        float nrm  = fmaxf(sqrtf(nrm2), 1e-8f);
        mu[b * NF + n]   = m;
        invn[b * NF + n] = 1.f / nrm;
    }
}

// ---------------------------------------------------------------------------
// mixed[n,m] = a*tanh(0.5*(C[n,m]+C[m,n]))
//            + (1-a)*clip( (1/B) sum_b inv[b,n]inv[b,m](S[b,n,m]-T mu_n mu_m), -1,1)
// Written to ws (for Laplacian) and to d_out tail (2nd output).
// ---------------------------------------------------------------------------
__global__ __launch_bounds__(256)
void mixed_kernel(const float* __restrict__ S, const float* __restrict__ mu,
                  const float* __restrict__ invn, const float* __restrict__ corrin,
                  const float* __restrict__ scal,
                  float* __restrict__ mixed_ws, float* __restrict__ mixed_out)
{
    const long idx = (long)blockIdx.x * 256 + threadIdx.x;  // over NF*NF
    const int nrow = (int)(idx >> 9);
    const int m    = (int)(idx & 511);

    float accum = 0.f;
    #pragma unroll 4
    for (int b = 0; b < BATCH; b++) {
        float sv = S[(long)b * NF * NF + idx];
        float t  = (sv - (float)TSEQ * mu[b * NF + nrow] * mu[b * NF + m])
                   * invn[b * NF + nrow] * invn[b * NF + m];
        accum += t;
    }
    accum *= (1.f / BATCH);
    accum = fminf(fmaxf(accum, -1.f), 1.f);

    float learned = tanhf(0.5f * (corrin[idx] + corrin[(long)m * NF + nrow]));
    float a = scal[3];
    float v = a * learned + (1.f - a) * accum;
    mixed_ws[idx]  = v;
    mixed_out[idx] = v;
}

// deg[n] = sum_m A[n,m] with zero diag; dis[n] = rsqrt(max(deg,EPS))
__global__ __launch_bounds__(128)
void deg_kernel(const float* __restrict__ mixed, float* __restrict__ dis)
{
    const int n = blockIdx.x, tid = threadIdx.x;
    const float* row = mixed + (long)n * NF;
    float4 v = *(const float4*)&row[tid * 4];
    float arr[4] = {v.x, v.y, v.z, v.w};
    float s = arr[0] + arr[1] + arr[2] + arr[3];
    if (tid == (n >> 2)) s -= arr[n & 3];
    #pragma unroll
    for (int off = 32; off > 0; off >>= 1) s += __shfl_down(s, off);
    __shared__ float ss[2];
    if ((tid & 63) == 0) ss[tid >> 6] = s;
    __syncthreads();
    if (tid == 0) {
        float deg = ss[0] + ss[1];
        dis[n] = rsqrtf(fmaxf(deg, 1e-8f));
    }
}

// L = clip(I - dis_n * A * dis_m, -2, 2), A = mixed with zero diag
__global__ __launch_bounds__(256)
void lap_kernel(const float* __restrict__ mixed, const float* __restrict__ dis,
                float* __restrict__ L)
{
    const long idx = (long)blockIdx.x * 256 + threadIdx.x;
    const int n = (int)(idx >> 9), m = (int)(idx & 511);
    float a = (n == m) ? 0.f : mixed[idx];
    float v = ((n == m) ? 1.f : 0.f) - dis[n] * a * dis[m];
    L[idx] = fminf(fmaxf(v, -2.f), 2.f);
}

// ---------------------------------------------------------------------------
// Generic f32 GEMM, 128x128 tile, BK=8, 256 threads, 8x8 micro-tile.
// MODE: 0 = NN (A[m,k], B[k,n]) | 1 = NT (A[m,k], B[n,k]) | 2 = TN (A[k,m], B[k,n])
// EPI:  0 = store | 1 = +bias[n] | 2 = cheb combine (needs ep0=xln, ep1=tx1, scal)
// All dims assumed multiples of tile sizes (true for this problem).
// ---------------------------------------------------------------------------
template<int MODE, int EPI>
__global__ __launch_bounds__(256)
void gemm128(const float* __restrict__ A, const float* __restrict__ B,
             float* __restrict__ C, int K, int lda, int ldb, int ldc,
             long sA, long sB, long sC,
             const float* __restrict__ ep0, const float* __restrict__ ep1,
             const float* __restrict__ scal)
{
    __shared__ float lsA[8][132];   // [BK][BM+4] pad keeps 16B alignment per row
    __shared__ float lsB[8][132];

    const int n0 = blockIdx.x * 128;
    const int m0 = blockIdx.y * 128;
    const int bz = blockIdx.z;
    A += (long)bz * sA; B += (long)bz * sB; C += (long)bz * sC;

    const int tid = threadIdx.x;
    const int tx = tid & 15, ty = tid >> 4;

    float acc[2][2][4][4];
    #pragma unroll
    for (int p = 0; p < 2; p++)
    #pragma unroll
    for (int q = 0; q < 2; q++)
    #pragma unroll
    for (int r = 0; r < 4; r++)
    #pragma unroll
    for (int c = 0; c < 4; c++) acc[p][q][r][c] = 0.f;

    for (int k0 = 0; k0 < K; k0 += 8) {
        if (MODE == 2) {  // A K-major: direct
            const int kk = tid >> 5, m4 = (tid & 31) << 2;
            float4 v = *(const float4*)&A[(long)(k0 + kk) * lda + m0 + m4];
            *(float4*)&lsA[kk][m4] = v;
        } else {          // A row-major: transpose on store
            const int mm = tid >> 1, k4 = (tid & 1) << 2;
            float4 v = *(const float4*)&A[(long)(m0 + mm) * lda + k0 + k4];
            lsA[k4 + 0][mm] = v.x; lsA[k4 + 1][mm] = v.y;
            lsA[k4 + 2][mm] = v.z; lsA[k4 + 3][mm] = v.w;
        }
        if (MODE == 1) {  // B is [n,k]: transpose on store
            const int nn = tid >> 1, k4 = (tid & 1) << 2;
            float4 v = *(const float4*)&B[(long)(n0 + nn) * ldb + k0 + k4];
            lsB[k4 + 0][nn] = v.x; lsB[k4 + 1][nn] = v.y;
            lsB[k4 + 2][nn] = v.z; lsB[k4 + 3][nn] = v.w;
        } else {          // B K-major: direct
            const int kk = tid >> 5, n4 = (tid & 31) << 2;
            float4 v = *(const float4*)&B[(long)(k0 + kk) * ldb + n0 + n4];
            *(float4*)&lsB[kk][n4] = v;
        }
        __syncthreads();

        #pragma unroll
        for (int kk = 0; kk < 8; kk++) {
            float4 a0 = *(const float4*)&lsA[kk][ty * 4];
            float4 a1 = *(const float4*)&lsA[kk][ty * 4 + 64];
            float4 b0 = *(const float4*)&lsB[kk][tx * 4];
            float4 b1 = *(const float4*)&lsB[kk][tx * 4 + 64];
            const float av[2][4] = {{a0.x,a0.y,a0.z,a0.w},{a1.x,a1.y,a1.z,a1.w}};
            const float bv[2][4] = {{b0.x,b0.y,b0.z,b0.w},{b1.x,b1.y,b1.z,b1.w}};
            #pragma unroll
            for (int p = 0; p < 2; p++)
            #pragma unroll
            for (int r = 0; r < 4; r++)
            #pragma unroll
            for (int q = 0; q < 2; q++)
            #pragma unroll
            for (int c = 0; c < 4; c++)
                acc[p][q][r][c] = fmaf(av[p][r], bv[q][c], acc[p][q][r][c]);
        }
        __syncthreads();
    }

    #pragma unroll
    for (int p = 0; p < 2; p++)
    #pragma unroll
    for (int r = 0; r < 4; r++) {
        const int m = m0 + p * 64 + ty * 4 + r;
        #pragma unroll
        for (int q = 0; q < 2; q++) {
            const int n = n0 + q * 64 + tx * 4;
            float vv[4];
            #pragma unroll
            for (int c = 0; c < 4; c++) {
                float v = acc[p][q][r][c];
                if (EPI == 1) v += ep0[n + c];
                if (EPI == 2) {
                    const float x0 = ep0[(long)m * ldc + n + c];
                    const float t1 = ep1[(long)m * ldc + n + c];
                    const float t2 = fminf(fmaxf(2.f * v - x0, -100.f), 100.f);
                    v = scal[0] * x0 + scal[1] * t1 + scal[2] * t2;
                }
                vv[c] = v;
            }
            float4 o; o.x = vv[0]; o.y = vv[1]; o.z = vv[2]; o.w = vv[3];
            *(float4*)&C[(long)m * ldc + n] = o;
        }
    }
}

// ---------------------------------------------------------------------------
extern "C" void kernel_launch(void* const* d_in, const int* in_sizes, int n_in,
                              void* d_out, int out_size, void* d_ws, size_t ws_size,
                              hipStream_t stream)
{
    const float* x     = (const float*)d_in[0];
    const float* corr  = (const float*)d_in[1];
    const float* alpha = (const float*)d_in[2];
    const float* cheb  = (const float*)d_in[3];
    const float* Wi    = (const float*)d_in[4];
    const float* bi    = (const float*)d_in[5];
    const float* Wo    = (const float*)d_in[6];
    const float* bo    = (const float*)d_in[7];
    const float* g1    = (const float*)d_in[8];
    const float* b1    = (const float*)d_in[9];
    const float* g2    = (const float*)d_in[10];
    const float* b2    = (const float*)d_in[11];
    const float* g3    = (const float*)d_in[12];
    const float* b3    = (const float*)d_in[13];
    float* out = (float*)d_out;

    // Workspace layout (floats). Overlays:
    //   Smat shares buf2 (S dead before cheb_out written)
    //   hpre spans xln+tx1 (both dead after cheb epilogue)
    float* ws   = (float*)d_ws;
    float* xln  = ws;                      // 33554432 f  (B,T,N)
    float* tx1  = ws + 33554432;           // 33554432 f
    float* buf2 = ws + 67108864;           // 33554432 f  (S -> cheb_out -> y_pre)
    float* Smat = buf2;                    //  8388608 f  (B,N,N)
    float* hpre = ws;                      // 67108864 f  (B,T,H) over xln+tx1
    float* muv    = ws + 100663296;        // 16384 f
    float* invn   = ws + 100679680;        // 16384 f
    float* mixedw = ws + 100696064;        // 262144 f
    float* Lmat   = ws + 100958208;        // 262144 f
    float* disv   = ws + 101220352;        // 512 f
    float* scal   = ws + 101220864;        // 4 f
    // total ~101220868 floats = ~386.2 MiB

    const long BTN = (long)TSEQ * NF;      // per-batch xln stride
    const long NN2 = (long)NF * NF;

    // 0) scalars
    scal_kernel<<<1, 1, 0, stream>>>(cheb, alpha, scal);
    // 1) x -> LN -> xln
    row_ln<NF, false><<<MROWS, NF/4, 0, stream>>>(x, xln, g1, b1);
    // 2) per-(b,n) time stats
    colstats<<<dim3(NF/64, BATCH), 256, 0, stream>>>(xln, muv, invn);
    // 3) batched Gram S_b = X_b^T X_b  (TN)
    gemm128<2, 0><<<dim3(NF/128, NF/128, BATCH), 256, 0, stream>>>(
        xln, xln, Smat, TSEQ, NF, NF, NF, BTN, BTN, NN2,
        nullptr, nullptr, nullptr);
    // 4) mixed (also writes 2nd output)
    mixed_kernel<<<(int)(NN2/256), 256, 0, stream>>>(Smat, muv, invn, corr, scal,
                                                     mixedw, out + (long)MROWS*ODIM);
    // 5) Laplacian
    deg_kernel<<<NF, 128, 0, stream>>>(mixedw, disv);
    lap_kernel<<<(int)(NN2/256), 256, 0, stream>>>(mixedw, disv, Lmat);
    // 6) Tx1 = xln @ L  (NN)
    gemm128<0, 0><<<dim3(NF/128, MROWS/128), 256, 0, stream>>>(
        xln, Lmat, tx1, NF, NF, NF, NF, 0, 0, 0, nullptr, nullptr, nullptr);
    // 7) cheb_out = w0*xln + w1*tx1 + w2*clip(2*(tx1@L) - xln)  (NN + epilogue)
    gemm128<0, 2><<<dim3(NF/128, MROWS/128), 256, 0, stream>>>(
        tx1, Lmat, buf2, NF, NF, NF, NF, 0, 0, 0, xln, tx1, scal);
    // 8) hpre = cheb_out @ Wi^T + bi  (NT)
    gemm128<1, 1><<<dim3(HDIM/128, MROWS/128), 256, 0, stream>>>(
        buf2, Wi, hpre, NF, NF, NF, HDIM, 0, 0, 0, bi, nullptr, nullptr);
    // 9) h = gelu(LN(hpre)) in place
    row_ln<HDIM, true><<<MROWS, HDIM/4, 0, stream>>>(hpre, hpre, g2, b2);
    // 10) y_pre = h @ Wo^T + bo  (NT)
    gemm128<1, 1><<<dim3(ODIM/128, MROWS/128), 256, 0, stream>>>(
        hpre, Wo, buf2, HDIM, HDIM, HDIM, ODIM, 0, 0, 0, bo, nullptr, nullptr);
    // 11) y = LN(y_pre) -> d_out
    row_ln<ODIM, false><<<MROWS, ODIM/4, 0, stream>>>(buf2, out, g3, b3);
}

// Round 3
// 1095.981 us; speedup vs baseline: 3.0530x; 3.0530x over previous
//
#include <hip/hip_runtime.h>
#include <math.h>

#define BATCH 32
#define TSEQ  2048
#define NF    512
#define HDIM  1024
#define ODIM  512
#define MROWS (BATCH*TSEQ)

typedef __attribute__((ext_vector_type(4))) float f32x4;
typedef __attribute__((ext_vector_type(8))) short bf16x8;      // 8 bf16 in 4 VGPRs
typedef __attribute__((ext_vector_type(4))) unsigned short us4;
typedef __attribute__((ext_vector_type(8))) unsigned short us8;

__device__ __forceinline__ float b2f(unsigned short u) {
    union { unsigned int i; float f; } v; v.i = ((unsigned int)u) << 16; return v.f;
}
__device__ __forceinline__ unsigned short f2b(float f) {
    union { float f; unsigned int i; } v; v.f = f;
    unsigned int r = v.i + 0x7fffu + ((v.i >> 16) & 1u);
    return (unsigned short)(r >> 16);
}

__device__ __forceinline__ void gload16(const void* g, const void* lds) {
    __builtin_amdgcn_global_load_lds(
        (const __attribute__((address_space(1))) unsigned int*)g,
        (__attribute__((address_space(3))) unsigned int*)lds, 16, 0, 0);
}

__device__ __forceinline__ f32x4 mfma16(bf16x8 a, bf16x8 b, f32x4 c) {
    return __builtin_amdgcn_mfma_f32_16x16x32_bf16(a, b, c, 0, 0, 0);
}

// ---------------------------------------------------------------------------
__global__ void scal_kernel(const float* __restrict__ chw,
                            const float* __restrict__ alpha,
                            float* __restrict__ scal)
{
    if (threadIdx.x == 0 && blockIdx.x == 0) {
        float c0 = chw[0], c1 = chw[1], c2 = chw[2];
        float m  = fmaxf(c0, fmaxf(c1, c2));
        float e0 = expf(c0 - m), e1 = expf(c1 - m), e2 = expf(c2 - m);
        float s  = e0 + e1 + e2;
        scal[0] = e0 / s; scal[1] = e1 / s; scal[2] = e2 / s;
        scal[3] = 1.f / (1.f + expf(-alpha[0]));
    }
}

__global__ __launch_bounds__(256)
void convw(const float* __restrict__ Wi, const float* __restrict__ Wo,
           unsigned short* __restrict__ Wib, unsigned short* __restrict__ Wob)
{
    const int i = blockIdx.x * 256 + threadIdx.x;   // 524288 each
    Wib[i] = f2b(Wi[i]);
    Wob[i] = f2b(Wo[i]);
}

// ---------------------------------------------------------------------------
// LN1: f32 x -> LN -> split to hi/lo bf16 (hi+lo ~= f32 value)
__global__ __launch_bounds__(128)
void ln1(const float* __restrict__ in, unsigned short* __restrict__ hi,
         unsigned short* __restrict__ lo, const float* __restrict__ g,
         const float* __restrict__ bb)
{
    __shared__ float ssum[2], ssq[2];
    const size_t row = blockIdx.x;
    const int tid = threadIdx.x;
    float4 v = *(const float4*)&in[row * NF + tid * 4];
    float s = v.x + v.y + v.z + v.w;
    float q = v.x*v.x + v.y*v.y + v.z*v.z + v.w*v.w;
    #pragma unroll
    for (int off = 32; off > 0; off >>= 1) { s += __shfl_down(s, off); q += __shfl_down(q, off); }
    if ((tid & 63) == 0) { ssum[tid >> 6] = s; ssq[tid >> 6] = q; }
    __syncthreads();
    const float st = ssum[0] + ssum[1], qt = ssq[0] + ssq[1];
    const float mean = st * (1.f / NF);
    const float var  = qt * (1.f / NF) - mean * mean;
    const float rstd = rsqrtf(var + 1e-5f);
    float4 gv = *(const float4*)&g[tid * 4];
    float4 bv = *(const float4*)&bb[tid * 4];
    float o[4];
    o[0] = (v.x - mean) * rstd * gv.x + bv.x;
    o[1] = (v.y - mean) * rstd * gv.y + bv.y;
    o[2] = (v.z - mean) * rstd * gv.z + bv.z;
    o[3] = (v.w - mean) * rstd * gv.w + bv.w;
    us4 ho, lo2;
    #pragma unroll
    for (int c = 0; c < 4; c++) {
        unsigned short hb = f2b(o[c]);
        ho[c] = hb;
        lo2[c] = f2b(o[c] - b2f(hb));
    }
    *(us4*)&hi[row * NF + tid * 4] = ho;
    *(us4*)&lo[row * NF + tid * 4] = lo2;
}

// LN2 + exact GeLU, bf16 in/out, W=1024
__global__ __launch_bounds__(256)
void ln2g(const unsigned short* __restrict__ in, unsigned short* __restrict__ outp,
          const float* __restrict__ g, const float* __restrict__ bb)
{
    __shared__ float ssum[4], ssq[4];
    const size_t row = blockIdx.x;
    const int tid = threadIdx.x;
    us4 u = *(const us4*)&in[row * HDIM + tid * 4];
    float x[4];
    #pragma unroll
    for (int c = 0; c < 4; c++) x[c] = b2f(u[c]);
    float s = x[0]+x[1]+x[2]+x[3];
    float q = x[0]*x[0]+x[1]*x[1]+x[2]*x[2]+x[3]*x[3];
    #pragma unroll
    for (int off = 32; off > 0; off >>= 1) { s += __shfl_down(s, off); q += __shfl_down(q, off); }
    if ((tid & 63) == 0) { ssum[tid >> 6] = s; ssq[tid >> 6] = q; }
    __syncthreads();
    const float st = ssum[0]+ssum[1]+ssum[2]+ssum[3];
    const float qt = ssq[0]+ssq[1]+ssq[2]+ssq[3];
    const float mean = st * (1.f / HDIM);
    const float var  = qt * (1.f / HDIM) - mean * mean;
    const float rstd = rsqrtf(var + 1e-5f);
    float4 gv = *(const float4*)&g[tid * 4];
    float4 bv = *(const float4*)&bb[tid * 4];
    const float gvv[4] = {gv.x, gv.y, gv.z, gv.w};
    const float bvv[4] = {bv.x, bv.y, bv.z, bv.w};
    us4 uo;
    #pragma unroll
    for (int c = 0; c < 4; c++) {
        float o = (x[c] - mean) * rstd * gvv[c] + bvv[c];
        o = 0.5f * o * (1.f + erff(o * 0.70710678118f));
        uo[c] = f2b(o);
    }
    *(us4*)&outp[row * HDIM + tid * 4] = uo;
}

// LN3: f32 -> f32, W=512
__global__ __launch_bounds__(128)
void ln3(const float* __restrict__ in, float* __restrict__ outp,
         const float* __restrict__ g, const float* __restrict__ bb)
{
    __shared__ float ssum[2], ssq[2];
    const size_t row = blockIdx.x;
    const int tid = threadIdx.x;
    float4 v = *(const float4*)&in[row * ODIM + tid * 4];
    float s = v.x + v.y + v.z + v.w;
    float q = v.x*v.x + v.y*v.y + v.z*v.z + v.w*v.w;
    #pragma unroll
    for (int off = 32; off > 0; off >>= 1) { s += __shfl_down(s, off); q += __shfl_down(q, off); }
    if ((tid & 63) == 0) { ssum[tid >> 6] = s; ssq[tid >> 6] = q; }
    __syncthreads();
    const float st = ssum[0] + ssum[1], qt = ssq[0] + ssq[1];
    const float mean = st * (1.f / ODIM);
    const float var  = qt * (1.f / ODIM) - mean * mean;
    const float rstd = rsqrtf(var + 1e-5f);
    float4 gv = *(const float4*)&g[tid * 4];
    float4 bv = *(const float4*)&bb[tid * 4];
    float4 o;
    o.x = (v.x - mean) * rstd * gv.x + bv.x;
    o.y = (v.y - mean) * rstd * gv.y + bv.y;
    o.z = (v.z - mean) * rstd * gv.z + bv.z;
    o.w = (v.w - mean) * rstd * gv.w + bv.w;
    *(float4*)&outp[row * ODIM + tid * 4] = o;
}

// ---------------------------------------------------------------------------
// 64x64 bf16 transpose: in [B*T][N] -> out [B][N][T]
__global__ __launch_bounds__(256)
void transpose_bt(const unsigned short* __restrict__ in, unsigned short* __restrict__ outp)
{
    __shared__ __align__(16) unsigned short tile[64][72];
    const int t0 = blockIdx.x * 64, nn0 = blockIdx.y * 64, b = blockIdx.z;
    const int tid = threadIdx.x;
    const int rr = tid >> 3, cc = (tid & 7) * 8;
    #pragma unroll
    for (int p = 0; p < 2; p++) {
        const int r = rr + p * 32;
        us8 v = *(const us8*)&in[((size_t)b * TSEQ + t0 + r) * NF + nn0 + cc];
        *(us8*)&tile[r][cc] = v;
    }
    __syncthreads();
    #pragma unroll
    for (int p = 0; p < 2; p++) {
        const int n = rr + p * 32;
        us8 v;
        #pragma unroll
        for (int j = 0; j < 8; j++) v[j] = tile[cc + j][n];
        *(us8*)&outp[((size_t)b * NF + nn0 + n) * TSEQ + t0 + cc] = v;
    }
}

// per-(b,n) time stats from transposed hi/lo: one wave per row of 2048
__global__ __launch_bounds__(256)
void colstats_t(const unsigned short* __restrict__ hiT, const unsigned short* __restrict__ loT,
                float* __restrict__ mu, float* __restrict__ invn)
{
    const int row = blockIdx.x * 4 + (threadIdx.x >> 6);
    const int l = threadIdx.x & 63;
    const unsigned short* ph = hiT + (size_t)row * TSEQ;
    const unsigned short* pl = loT + (size_t)row * TSEQ;
    float s = 0.f, q = 0.f;
    #pragma unroll
    for (int i = 0; i < 4; i++) {
        const int off = i * 512 + l * 8;
        us8 h = *(const us8*)&ph[off];
        us8 lv = *(const us8*)&pl[off];
        #pragma unroll
        for (int j = 0; j < 8; j++) {
            float xv = b2f(h[j]) + b2f(lv[j]);
            s += xv; q += xv * xv;
        }
    }
    #pragma unroll
    for (int off = 32; off > 0; off >>= 1) { s += __shfl_down(s, off); q += __shfl_down(q, off); }
    if (l == 0) {
        const float m  = s * (1.f / TSEQ);
        const float n2 = fmaxf(q - (float)TSEQ * m * m, 0.f);
        const float nr = fmaxf(sqrtf(n2), 1e-8f);
        mu[row]   = m;
        invn[row] = 1.f / nr;
    }
}

// ---------------------------------------------------------------------------
__global__ __launch_bounds__(256)
void mixed_kernel(const float* __restrict__ S, const float* __restrict__ corrin,
                  const float* __restrict__ scal,
                  float* __restrict__ mixed_ws, float* __restrict__ mixed_out)
{
    const long idx = (long)blockIdx.x * 256 + threadIdx.x;
    const int i = (int)(idx >> 9), j = (int)(idx & 511);
    float accum = 0.f;
    #pragma unroll 8
    for (int b = 0; b < BATCH; b++) accum += S[(long)b * NF * NF + idx];
    accum = fminf(fmaxf(accum, -1.f), 1.f);
    const float learned = tanhf(0.5f * (corrin[idx] + corrin[(long)j * NF + i]));
    const float a = scal[3];
    const float v = a * learned + (1.f - a) * accum;
    mixed_ws[idx]  = v;
    mixed_out[idx] = v;
}

__global__ __launch_bounds__(128)
void deg_kernel(const float* __restrict__ mixed, float* __restrict__ dis)
{
    const int n = blockIdx.x, tid = threadIdx.x;
    const float* row = mixed + (long)n * NF;
    float4 v = *(const float4*)&row[tid * 4];
    float arr[4] = {v.x, v.y, v.z, v.w};
    float s = arr[0] + arr[1] + arr[2] + arr[3];
    if (tid == (n >> 2)) s -= arr[n & 3];
    #pragma unroll
    for (int off = 32; off > 0; off >>= 1) s += __shfl_down(s, off);
    __shared__ float ss[2];
    if ((tid & 63) == 0) ss[tid >> 6] = s;
    __syncthreads();
    if (tid == 0) dis[n] = rsqrtf(fmaxf(ss[0] + ss[1], 1e-8f));
}

// L split to hi/lo bf16 so the Tx GEMMs can run compensated
__global__ __launch_bounds__(256)
void lap_kernel(const float* __restrict__ mixed, const float* __restrict__ dis,
                unsigned short* __restrict__ Lhi, unsigned short* __restrict__ Llo)
{
    const long idx = (long)blockIdx.x * 256 + threadIdx.x;
    const int n = (int)(idx >> 9), m = (int)(idx & 511);
    const float a = (n == m) ? 0.f : mixed[idx];
    float v = ((n == m) ? 1.f : 0.f) - dis[n] * a * dis[m];
    v = fminf(fmaxf(v, -2.f), 2.f);
    const unsigned short hb = f2b(v);
    Lhi[idx] = hb;
    Llo[idx] = f2b(v - b2f(hb));
}

// ---------------------------------------------------------------------------
// bf16 MFMA GEMM, NT form: C[m][n] = sum_k A[m][k]*B[n][k].
// 128x128 tile, BK=64, 256 threads (4 waves, 2x2 of 64x64), 16x16x32 MFMA.
// LDS chunk-XOR swizzle (pc = c ^ (row&7)) applied on BOTH the
// global_load_lds source and the ds_read address (involution).
// COMP: compensated split A=A+A2, B=B+B2 -> acc = A*B + A*B2 + A2*B.
// EPI: 0 Gram->normalized per-batch f32 S; 1 hi/lo split bf16 store;
//      2 cheb combine; 3 +bias bf16 store; 4 +bias f32 store.
template<int EPI, bool COMP>
__global__ __launch_bounds__(256)
void mgemm(const unsigned short* __restrict__ A, const unsigned short* __restrict__ B,
           const unsigned short* __restrict__ A2, const unsigned short* __restrict__ B2,
           void* __restrict__ Cp, void* __restrict__ Cp2,
           int K, int lda, int ldb, int ldc,
           long sA, long sB, long sC,
           const float* __restrict__ e0, const float* __restrict__ e1,
           const unsigned short* __restrict__ u0, const unsigned short* __restrict__ u1,
           const unsigned short* __restrict__ u2, const unsigned short* __restrict__ u3,
           const float* __restrict__ scal)
{
    __shared__ __align__(16) unsigned short lsA[128 * 64];
    __shared__ __align__(16) unsigned short lsB[128 * 64];
    __shared__ __align__(16) unsigned short lsA2[COMP ? 128 * 64 : 8];
    __shared__ __align__(16) unsigned short lsB2[COMP ? 128 * 64 : 8];

    const int tid = threadIdx.x;
    const int w = tid >> 6, l = tid & 63;
    const int n0 = blockIdx.x * 128, m0 = blockIdx.y * 128;
    const long bz = blockIdx.z;
    A += bz * sA; B += bz * sB;
    if (COMP) { A2 += bz * sA; B2 += bz * sB; }
    const int wm = (w >> 1) * 64, wn = (w & 1) * 64;
    const int l15 = l & 15, l4 = l >> 4;
    const int srow = l >> 3, pc = l & 7;

    f32x4 acc[4][4];
    #pragma unroll
    for (int i = 0; i < 4; i++)
        #pragma unroll
        for (int j = 0; j < 4; j++) acc[i][j] = (f32x4)(0.f);

    for (int k0 = 0; k0 < K; k0 += 64) {
        #pragma unroll
        for (int it = 0; it < 4; it++) {
            const int rb = w * 32 + it * 8;
            const int r  = rb + srow;
            const int c  = pc ^ (r & 7);
            gload16(A + (size_t)(m0 + r) * lda + k0 + c * 8, &lsA[rb * 64]);
            gload16(B + (size_t)(n0 + r) * ldb + k0 + c * 8, &lsB[rb * 64]);
            if (COMP) {
                gload16(A2 + (size_t)(m0 + r) * lda + k0 + c * 8, &lsA2[rb * 64]);
                gload16(B2 + (size_t)(n0 + r) * ldb + k0 + c * 8, &lsB2[rb * 64]);
            }
        }
        __syncthreads();
        #pragma unroll
        for (int kk = 0; kk < 2; kk++) {
            bf16x8 fa[4], fb[4], fa2[4], fb2[4];
            #pragma unroll
            for (int i = 0; i < 4; i++) {
                const int ra = wm + i * 16 + l15;
                const int qa = (kk * 4 + l4) ^ (ra & 7);
                fa[i] = *(const bf16x8*)&lsA[ra * 64 + qa * 8];
                const int rb2 = wn + i * 16 + l15;
                const int qb = (kk * 4 + l4) ^ (rb2 & 7);
                fb[i] = *(const bf16x8*)&lsB[rb2 * 64 + qb * 8];
                if (COMP) {
                    fa2[i] = *(const bf16x8*)&lsA2[ra * 64 + qa * 8];
                    fb2[i] = *(const bf16x8*)&lsB2[rb2 * 64 + qb * 8];
                }
            }
            #pragma unroll
            for (int i = 0; i < 4; i++)
                #pragma unroll
                for (int j = 0; j < 4; j++) {
                    acc[i][j] = mfma16(fa[i], fb[j], acc[i][j]);
                    if (COMP) {
                        acc[i][j] = mfma16(fa[i], fb2[j], acc[i][j]);
                        acc[i][j] = mfma16(fa2[i], fb[j], acc[i][j]);
                    }
                }
        }
        __syncthreads();
    }

    // epilogue: C/D layout col = l&15, row = (l>>4)*4 + r  [m89/m91]
    #pragma unroll
    for (int i = 0; i < 4; i++) {
        #pragma unroll
        for (int j = 0; j < 4; j++) {
            #pragma unroll
            for (int r = 0; r < 4; r++) {
                const int mrow = m0 + wm + i * 16 + l4 * 4 + r;
                const int ncol = n0 + wn + j * 16 + l15;
                const float v = acc[i][j][r];
                if (EPI == 0) {
                    float* C = (float*)Cp + bz * sC;
                    const float mui = e0[bz * NF + mrow], muj = e0[bz * NF + ncol];
                    const float ii  = e1[bz * NF + mrow], ij  = e1[bz * NF + ncol];
                    C[(size_t)mrow * ldc + ncol] =
                        (v - (float)TSEQ * mui * muj) * ii * ij * (1.f / BATCH);
                } else if (EPI == 1) {
                    const size_t idx = (size_t)mrow * ldc + ncol;
                    const unsigned short hb = f2b(v);
                    ((unsigned short*)Cp)[idx]  = hb;
                    ((unsigned short*)Cp2)[idx] = f2b(v - b2f(hb));
                } else if (EPI == 2) {
                    const size_t idx = (size_t)mrow * ldc + ncol;
                    const float x0 = b2f(u0[idx]) + b2f(u1[idx]);
                    const float t1 = b2f(u2[idx]) + b2f(u3[idx]);
                    const float t2 = fminf(fmaxf(2.f * v - x0, -100.f), 100.f);
                    ((unsigned short*)Cp)[idx] = f2b(scal[0] * x0 + scal[1] * t1 + scal[2] * t2);
                } else if (EPI == 3) {
                    ((unsigned short*)Cp)[(size_t)mrow * ldc + ncol] = f2b(v + e0[ncol]);
                } else {
                    ((float*)Cp)[(size_t)mrow * ldc + ncol] = v + e0[ncol];
                }
            }
        }
    }
}

// ---------------------------------------------------------------------------
extern "C" void kernel_launch(void* const* d_in, const int* in_sizes, int n_in,
                              void* d_out, int out_size, void* d_ws, size_t ws_size,
                              hipStream_t stream)
{
    const float* x     = (const float*)d_in[0];
    const float* corr  = (const float*)d_in[1];
    const float* alpha = (const float*)d_in[2];
    const float* chw   = (const float*)d_in[3];
    const float* Wi    = (const float*)d_in[4];
    const float* bi    = (const float*)d_in[5];
    const float* Wo    = (const float*)d_in[6];
    const float* bo    = (const float*)d_in[7];
    const float* g1    = (const float*)d_in[8];
    const float* b1    = (const float*)d_in[9];
    const float* g2    = (const float*)d_in[10];
    const float* b2    = (const float*)d_in[11];
    const float* g3    = (const float*)d_in[12];
    const float* b3    = (const float*)d_in[13];
    float* out = (float*)d_out;

    // ws layout (MiB offsets). Overlays:
    //   0..128   hi(64)+lo(64)         -> hpre (bf16, 128)   -> ypre (f32, 128)
    //   128..256 hiT(64)+loT(64)       -> tx1hi(64)+tx1lo(64) -> hbuf (bf16, 128)
    //   256..320 chb (64)
    //   320..352 Smat (f32, 32)
    //   352+     small tensors
    char* wsb = (char*)d_ws;
    const size_t MB = 1024ull * 1024ull;
    unsigned short* hi    = (unsigned short*)(wsb + 0);
    unsigned short* lo    = (unsigned short*)(wsb + 64 * MB);
    unsigned short* hiT   = (unsigned short*)(wsb + 128 * MB);
    unsigned short* loT   = (unsigned short*)(wsb + 192 * MB);
    unsigned short* tx1hi = hiT;
    unsigned short* tx1lo = loT;
    unsigned short* chb   = (unsigned short*)(wsb + 256 * MB);
    unsigned short* hpre  = hi;                                // 128 MiB
    unsigned short* hbuf  = hiT;                               // 128 MiB
    float*          ypre  = (float*)(wsb + 0);                 // 128 MiB
    float* Smat   = (float*)(wsb + 320 * MB);                  // 32 MiB
    float* muv    = (float*)(wsb + 352 * MB);                  // 64 KiB
    float* invn   = (float*)(wsb + 352 * MB + 65536);          // 64 KiB
    float* mixedw = (float*)(wsb + 353 * MB);                  // 1 MiB
    float* disv   = (float*)(wsb + 354 * MB);                  // 2 KiB
    float* scal   = (float*)(wsb + 354 * MB + 4096);           // 16 B
    unsigned short* Lhi = (unsigned short*)(wsb + 355 * MB);   // 512 KiB
    unsigned short* Llo = (unsigned short*)(wsb + 355 * MB + 524288); // 512 KiB
    unsigned short* Wib = (unsigned short*)(wsb + 356 * MB);   // 1 MiB
    unsigned short* Wob = (unsigned short*)(wsb + 357 * MB);   // 1 MiB -> 358 MiB total

    const long NT2 = (long)NF * TSEQ;   // 1048576
    const long NN2 = (long)NF * NF;     // 262144

    scal_kernel<<<1, 1, 0, stream>>>(chw, alpha, scal);
    convw<<<2048, 256, 0, stream>>>(Wi, Wo, Wib, Wob);

    ln1<<<MROWS, 128, 0, stream>>>(x, hi, lo, g1, b1);
    transpose_bt<<<dim3(32, 8, 32), 256, 0, stream>>>(hi, hiT);
    transpose_bt<<<dim3(32, 8, 32), 256, 0, stream>>>(lo, loT);
    colstats_t<<<4096, 256, 0, stream>>>(hiT, loT, muv, invn);

    // Gram (compensated): per-batch normalized S, summed in mixed_kernel
    mgemm<0, true><<<dim3(4, 4, 32), 256, 0, stream>>>(
        hiT, hiT, loT, loT, Smat, nullptr, TSEQ, TSEQ, TSEQ, NF, NT2, NT2, NN2,
        muv, invn, nullptr, nullptr, nullptr, nullptr, nullptr);

    mixed_kernel<<<1024, 256, 0, stream>>>(Smat, corr, scal, mixedw,
                                           out + (long)MROWS * ODIM);
    deg_kernel<<<NF, 128, 0, stream>>>(mixedw, disv);
    lap_kernel<<<1024, 256, 0, stream>>>(mixedw, disv, Lhi, Llo);

    // Tx1 = xln @ L  (compensated, hi/lo split output)
    mgemm<1, true><<<dim3(4, 512), 256, 0, stream>>>(
        hi, Lhi, lo, Llo, tx1hi, tx1lo, NF, NF, NF, NF, 0, 0, 0,
        nullptr, nullptr, nullptr, nullptr, nullptr, nullptr, nullptr);
    // cheb_out = w0*x + w1*Tx1 + w2*clip(2*Tx1@L - x)  (compensated)
    mgemm<2, true><<<dim3(4, 512), 256, 0, stream>>>(
        tx1hi, Lhi, tx1lo, Llo, chb, nullptr, NF, NF, NF, NF, 0, 0, 0,
        nullptr, nullptr, hi, lo, tx1hi, tx1lo, scal);
    // hpre = cheb @ Wi^T + bi  (plain bf16)
    mgemm<3, false><<<dim3(8, 512), 256, 0, stream>>>(
        chb, Wib, nullptr, nullptr, hpre, nullptr, NF, NF, NF, HDIM, 0, 0, 0,
        bi, nullptr, nullptr, nullptr, nullptr, nullptr, nullptr);
    ln2g<<<MROWS, 256, 0, stream>>>(hpre, hbuf, g2, b2);
    // ypre = h @ Wo^T + bo  (plain bf16, f32 out)
    mgemm<4, false><<<dim3(4, 512), 256, 0, stream>>>(
        hbuf, Wob, nullptr, nullptr, ypre, nullptr, HDIM, HDIM, HDIM, ODIM, 0, 0, 0,
        bo, nullptr, nullptr, nullptr, nullptr, nullptr, nullptr);
    ln3<<<MROWS, 128, 0, stream>>>(ypre, out, g3, b3);
}

// Round 4
// 1026.744 us; speedup vs baseline: 3.2589x; 1.0674x over previous
//
#include <hip/hip_runtime.h>
#include <math.h>

#define BATCH 32
#define TSEQ  2048
#define NF    512
#define HDIM  1024
#define ODIM  512
#define MROWS (BATCH*TSEQ)

typedef __attribute__((ext_vector_type(4))) float f32x4;
typedef __attribute__((ext_vector_type(8))) short bf16x8;      // 8 bf16 in 4 VGPRs
typedef __attribute__((ext_vector_type(4))) unsigned short us4;
typedef __attribute__((ext_vector_type(8))) unsigned short us8;

template<int V> struct Log2 { static constexpr int v = 1 + Log2<V/2>::v; };
template<> struct Log2<1> { static constexpr int v = 0; };

__device__ __forceinline__ float b2f(unsigned short u) {
    union { unsigned int i; float f; } v; v.i = ((unsigned int)u) << 16; return v.f;
}
__device__ __forceinline__ unsigned short f2b(float f) {
    union { float f; unsigned int i; } v; v.f = f;
    unsigned int r = v.i + 0x7fffu + ((v.i >> 16) & 1u);
    return (unsigned short)(r >> 16);
}

__device__ __forceinline__ void gload16(const void* g, const void* lds) {
    __builtin_amdgcn_global_load_lds(
        (const __attribute__((address_space(1))) unsigned int*)g,
        (__attribute__((address_space(3))) unsigned int*)lds, 16, 0, 0);
}

__device__ __forceinline__ f32x4 mfma16(bf16x8 a, bf16x8 b, f32x4 c) {
    return __builtin_amdgcn_mfma_f32_16x16x32_bf16(a, b, c, 0, 0, 0);
}

// ---------------------------------------------------------------------------
__global__ void scal_kernel(const float* __restrict__ chw,
                            const float* __restrict__ alpha,
                            float* __restrict__ scal)
{
    if (threadIdx.x == 0 && blockIdx.x == 0) {
        float c0 = chw[0], c1 = chw[1], c2 = chw[2];
        float m  = fmaxf(c0, fmaxf(c1, c2));
        float e0 = expf(c0 - m), e1 = expf(c1 - m), e2 = expf(c2 - m);
        float s  = e0 + e1 + e2;
        scal[0] = e0 / s; scal[1] = e1 / s; scal[2] = e2 / s;
        scal[3] = 1.f / (1.f + expf(-alpha[0]));
    }
}

__global__ __launch_bounds__(256)
void convw(const float* __restrict__ Wi, const float* __restrict__ Wo,
           unsigned short* __restrict__ Wib, unsigned short* __restrict__ Wob)
{
    const int i = blockIdx.x * 256 + threadIdx.x;   // 524288 each
    Wib[i] = f2b(Wi[i]);
    Wob[i] = f2b(Wo[i]);
}

// ---------------------------------------------------------------------------
// LN1: f32 x -> LN -> split to hi/lo bf16 (hi+lo ~= f32 value)
__global__ __launch_bounds__(128)
void ln1(const float* __restrict__ in, unsigned short* __restrict__ hi,
         unsigned short* __restrict__ lo, const float* __restrict__ g,
         const float* __restrict__ bb)
{
    __shared__ float ssum[2], ssq[2];
    const size_t row = blockIdx.x;
    const int tid = threadIdx.x;
    float4 v = *(const float4*)&in[row * NF + tid * 4];
    float s = v.x + v.y + v.z + v.w;
    float q = v.x*v.x + v.y*v.y + v.z*v.z + v.w*v.w;
    #pragma unroll
    for (int off = 32; off > 0; off >>= 1) { s += __shfl_down(s, off); q += __shfl_down(q, off); }
    if ((tid & 63) == 0) { ssum[tid >> 6] = s; ssq[tid >> 6] = q; }
    __syncthreads();
    const float st = ssum[0] + ssum[1], qt = ssq[0] + ssq[1];
    const float mean = st * (1.f / NF);
    const float var  = qt * (1.f / NF) - mean * mean;
    const float rstd = rsqrtf(var + 1e-5f);
    float4 gv = *(const float4*)&g[tid * 4];
    float4 bv = *(const float4*)&bb[tid * 4];
    float o[4];
    o[0] = (v.x - mean) * rstd * gv.x + bv.x;
    o[1] = (v.y - mean) * rstd * gv.y + bv.y;
    o[2] = (v.z - mean) * rstd * gv.z + bv.z;
    o[3] = (v.w - mean) * rstd * gv.w + bv.w;
    us4 ho, lo2;
    #pragma unroll
    for (int c = 0; c < 4; c++) {
        unsigned short hb = f2b(o[c]);
        ho[c] = hb;
        lo2[c] = f2b(o[c] - b2f(hb));
    }
    *(us4*)&hi[row * NF + tid * 4] = ho;
    *(us4*)&lo[row * NF + tid * 4] = lo2;
}

// LN2 + exact GeLU, bf16 in/out, W=1024
__global__ __launch_bounds__(256)
void ln2g(const unsigned short* __restrict__ in, unsigned short* __restrict__ outp,
          const float* __restrict__ g, const float* __restrict__ bb)
{
    __shared__ float ssum[4], ssq[4];
    const size_t row = blockIdx.x;
    const int tid = threadIdx.x;
    us4 u = *(const us4*)&in[row * HDIM + tid * 4];
    float x[4];
    #pragma unroll
    for (int c = 0; c < 4; c++) x[c] = b2f(u[c]);
    float s = x[0]+x[1]+x[2]+x[3];
    float q = x[0]*x[0]+x[1]*x[1]+x[2]*x[2]+x[3]*x[3];
    #pragma unroll
    for (int off = 32; off > 0; off >>= 1) { s += __shfl_down(s, off); q += __shfl_down(q, off); }
    if ((tid & 63) == 0) { ssum[tid >> 6] = s; ssq[tid >> 6] = q; }
    __syncthreads();
    const float st = ssum[0]+ssum[1]+ssum[2]+ssum[3];
    const float qt = ssq[0]+ssq[1]+ssq[2]+ssq[3];
    const float mean = st * (1.f / HDIM);
    const float var  = qt * (1.f / HDIM) - mean * mean;
    const float rstd = rsqrtf(var + 1e-5f);
    float4 gv = *(const float4*)&g[tid * 4];
    float4 bv = *(const float4*)&bb[tid * 4];
    const float gvv[4] = {gv.x, gv.y, gv.z, gv.w};
    const float bvv[4] = {bv.x, bv.y, bv.z, bv.w};
    us4 uo;
    #pragma unroll
    for (int c = 0; c < 4; c++) {
        float o = (x[c] - mean) * rstd * gvv[c] + bvv[c];
        o = 0.5f * o * (1.f + erff(o * 0.70710678118f));
        uo[c] = f2b(o);
    }
    *(us4*)&outp[row * HDIM + tid * 4] = uo;
}

// LN3: f32 -> f32, W=512
__global__ __launch_bounds__(128)
void ln3(const float* __restrict__ in, float* __restrict__ outp,
         const float* __restrict__ g, const float* __restrict__ bb)
{
    __shared__ float ssum[2], ssq[2];
    const size_t row = blockIdx.x;
    const int tid = threadIdx.x;
    float4 v = *(const float4*)&in[row * ODIM + tid * 4];
    float s = v.x + v.y + v.z + v.w;
    float q = v.x*v.x + v.y*v.y + v.z*v.z + v.w*v.w;
    #pragma unroll
    for (int off = 32; off > 0; off >>= 1) { s += __shfl_down(s, off); q += __shfl_down(q, off); }
    if ((tid & 63) == 0) { ssum[tid >> 6] = s; ssq[tid >> 6] = q; }
    __syncthreads();
    const float st = ssum[0] + ssum[1], qt = ssq[0] + ssq[1];
    const float mean = st * (1.f / ODIM);
    const float var  = qt * (1.f / ODIM) - mean * mean;
    const float rstd = rsqrtf(var + 1e-5f);
    float4 gv = *(const float4*)&g[tid * 4];
    float4 bv = *(const float4*)&bb[tid * 4];
    float4 o;
    o.x = (v.x - mean) * rstd * gv.x + bv.x;
    o.y = (v.y - mean) * rstd * gv.y + bv.y;
    o.z = (v.z - mean) * rstd * gv.z + bv.z;
    o.w = (v.w - mean) * rstd * gv.w + bv.w;
    *(float4*)&outp[row * ODIM + tid * 4] = o;
}

// ---------------------------------------------------------------------------
// 64x64 bf16 transpose: in [B*T][N] -> out [B][N][T]
__global__ __launch_bounds__(256)
void transpose_bt(const unsigned short* __restrict__ in, unsigned short* __restrict__ outp)
{
    __shared__ __align__(16) unsigned short tile[64][72];
    const int t0 = blockIdx.x * 64, nn0 = blockIdx.y * 64, b = blockIdx.z;
    const int tid = threadIdx.x;
    const int rr = tid >> 3, cc = (tid & 7) * 8;
    #pragma unroll
    for (int p = 0; p < 2; p++) {
        const int r = rr + p * 32;
        us8 v = *(const us8*)&in[((size_t)b * TSEQ + t0 + r) * NF + nn0 + cc];
        *(us8*)&tile[r][cc] = v;
    }
    __syncthreads();
    #pragma unroll
    for (int p = 0; p < 2; p++) {
        const int n = rr + p * 32;
        us8 v;
        #pragma unroll
        for (int j = 0; j < 8; j++) v[j] = tile[cc + j][n];
        *(us8*)&outp[((size_t)b * NF + nn0 + n) * TSEQ + t0 + cc] = v;
    }
}

// per-(b,n) time stats from transposed hi/lo: one wave per row of 2048
__global__ __launch_bounds__(256)
void colstats_t(const unsigned short* __restrict__ hiT, const unsigned short* __restrict__ loT,
                float* __restrict__ mu, float* __restrict__ invn)
{
    const int row = blockIdx.x * 4 + (threadIdx.x >> 6);
    const int l = threadIdx.x & 63;
    const unsigned short* ph = hiT + (size_t)row * TSEQ;
    const unsigned short* pl = loT + (size_t)row * TSEQ;
    float s = 0.f, q = 0.f;
    #pragma unroll
    for (int i = 0; i < 4; i++) {
        const int off = i * 512 + l * 8;
        us8 h = *(const us8*)&ph[off];
        us8 lv = *(const us8*)&pl[off];
        #pragma unroll
        for (int j = 0; j < 8; j++) {
            float xv = b2f(h[j]) + b2f(lv[j]);
            s += xv; q += xv * xv;
        }
    }
    #pragma unroll
    for (int off = 32; off > 0; off >>= 1) { s += __shfl_down(s, off); q += __shfl_down(q, off); }
    if (l == 0) {
        const float m  = s * (1.f / TSEQ);
        const float n2 = fmaxf(q - (float)TSEQ * m * m, 0.f);
        const float nr = fmaxf(sqrtf(n2), 1e-8f);
        mu[row]   = m;
        invn[row] = 1.f / nr;
    }
}

// ---------------------------------------------------------------------------
__global__ __launch_bounds__(256)
void mixed_kernel(const float* __restrict__ S, const float* __restrict__ corrin,
                  const float* __restrict__ scal,
                  float* __restrict__ mixed_ws, float* __restrict__ mixed_out)
{
    const long idx = (long)blockIdx.x * 256 + threadIdx.x;
    const int i = (int)(idx >> 9), j = (int)(idx & 511);
    float accum = 0.f;
    #pragma unroll 8
    for (int b = 0; b < BATCH; b++) accum += S[(long)b * NF * NF + idx];
    accum = fminf(fmaxf(accum, -1.f), 1.f);
    const float learned = tanhf(0.5f * (corrin[idx] + corrin[(long)j * NF + i]));
    const float a = scal[3];
    const float v = a * learned + (1.f - a) * accum;
    mixed_ws[idx]  = v;
    mixed_out[idx] = v;
}

__global__ __launch_bounds__(128)
void deg_kernel(const float* __restrict__ mixed, float* __restrict__ dis)
{
    const int n = blockIdx.x, tid = threadIdx.x;
    const float* row = mixed + (long)n * NF;
    float4 v = *(const float4*)&row[tid * 4];
    float arr[4] = {v.x, v.y, v.z, v.w};
    float s = arr[0] + arr[1] + arr[2] + arr[3];
    if (tid == (n >> 2)) s -= arr[n & 3];
    #pragma unroll
    for (int off = 32; off > 0; off >>= 1) s += __shfl_down(s, off);
    __shared__ float ss[2];
    if ((tid & 63) == 0) ss[tid >> 6] = s;
    __syncthreads();
    if (tid == 0) dis[n] = rsqrtf(fmaxf(ss[0] + ss[1], 1e-8f));
}

// L split to hi/lo bf16 so the Tx GEMMs can run compensated
__global__ __launch_bounds__(256)
void lap_kernel(const float* __restrict__ mixed, const float* __restrict__ dis,
                unsigned short* __restrict__ Lhi, unsigned short* __restrict__ Llo)
{
    const long idx = (long)blockIdx.x * 256 + threadIdx.x;
    const int n = (int)(idx >> 9), m = (int)(idx & 511);
    const float a = (n == m) ? 0.f : mixed[idx];
    float v = ((n == m) ? 1.f : 0.f) - dis[n] * a * dis[m];
    v = fminf(fmaxf(v, -2.f), 2.f);
    const unsigned short hb = f2b(v);
    Lhi[idx] = hb;
    Llo[idx] = f2b(v - b2f(hb));
}

// ---------------------------------------------------------------------------
// bf16 MFMA GEMM, NT form: C[m][n] = sum_k A[m][k]*B[n][k].
// 128x128 tile, BK=64, 256 threads (4 waves, 2x2 of 64x64), 16x16x32 MFMA.
// LDS chunk-XOR swizzle (pc = c ^ (row&7)) applied on BOTH the
// global_load_lds source and the ds_read address (involution).
// COMP: compensated split A=A+A2, B=B+B2 -> acc = A*B + A*B2 + A2*B.
// 1-D grid with bijective XCD swizzle (T1): id' = (id%8)*(nwg/8) + id/8,
// decoded x-fastest with compile-time GX/GY so panel-sharing blocks
// co-reside on one XCD (kills the 3x A-panel over-fetch).
// EPI: 0 Gram->normalized per-batch f32 S; 1 hi/lo split bf16 store;
//      2 cheb combine; 3 +bias bf16 store; 4 +bias f32 store.
template<int EPI, bool COMP, int GX, int GY>
__global__ __launch_bounds__(256)
void mgemm(const unsigned short* __restrict__ A, const unsigned short* __restrict__ B,
           const unsigned short* __restrict__ A2, const unsigned short* __restrict__ B2,
           void* __restrict__ Cp, void* __restrict__ Cp2,
           int K, int lda, int ldb, int ldc,
           long sA, long sB, long sC,
           const float* __restrict__ e0, const float* __restrict__ e1,
           const unsigned short* __restrict__ u0, const unsigned short* __restrict__ u1,
           const unsigned short* __restrict__ u2, const unsigned short* __restrict__ u3,
           const float* __restrict__ scal)
{
    __shared__ __align__(16) unsigned short lsA[128 * 64];
    __shared__ __align__(16) unsigned short lsB[128 * 64];
    __shared__ __align__(16) unsigned short lsA2[COMP ? 128 * 64 : 8];
    __shared__ __align__(16) unsigned short lsB2[COMP ? 128 * 64 : 8];

    const int tid = threadIdx.x;
    const int w = tid >> 6, l = tid & 63;

    // --- XCD-aware bijective block remap (nwg is always a multiple of 8) ---
    const unsigned nwg = gridDim.x;
    unsigned id = blockIdx.x;
    id = (id & 7u) * (nwg >> 3) + (id >> 3);
    const int bxi = id & (GX - 1);
    const int byi = (id >> Log2<GX>::v) & (GY - 1);
    const int bzi = (int)(id >> (Log2<GX>::v + Log2<GY>::v));

    const int n0 = bxi * 128, m0 = byi * 128;
    const long bz = bzi;
    A += bz * sA; B += bz * sB;
    if (COMP) { A2 += bz * sA; B2 += bz * sB; }
    const int wm = (w >> 1) * 64, wn = (w & 1) * 64;
    const int l15 = l & 15, l4 = l >> 4;
    const int srow = l >> 3, pc = l & 7;

    f32x4 acc[4][4];
    #pragma unroll
    for (int i = 0; i < 4; i++)
        #pragma unroll
        for (int j = 0; j < 4; j++) acc[i][j] = (f32x4)(0.f);

    for (int k0 = 0; k0 < K; k0 += 64) {
        #pragma unroll
        for (int it = 0; it < 4; it++) {
            const int rb = w * 32 + it * 8;
            const int r  = rb + srow;
            const int c  = pc ^ (r & 7);
            gload16(A + (size_t)(m0 + r) * lda + k0 + c * 8, &lsA[rb * 64]);
            gload16(B + (size_t)(n0 + r) * ldb + k0 + c * 8, &lsB[rb * 64]);
            if (COMP) {
                gload16(A2 + (size_t)(m0 + r) * lda + k0 + c * 8, &lsA2[rb * 64]);
                gload16(B2 + (size_t)(n0 + r) * ldb + k0 + c * 8, &lsB2[rb * 64]);
            }
        }
        __syncthreads();
        #pragma unroll
        for (int kk = 0; kk < 2; kk++) {
            bf16x8 fa[4], fb[4], fa2[4], fb2[4];
            #pragma unroll
            for (int i = 0; i < 4; i++) {
                const int ra = wm + i * 16 + l15;
                const int qa = (kk * 4 + l4) ^ (ra & 7);
                fa[i] = *(const bf16x8*)&lsA[ra * 64 + qa * 8];
                const int rb2 = wn + i * 16 + l15;
                const int qb = (kk * 4 + l4) ^ (rb2 & 7);
                fb[i] = *(const bf16x8*)&lsB[rb2 * 64 + qb * 8];
                if (COMP) {
                    fa2[i] = *(const bf16x8*)&lsA2[ra * 64 + qa * 8];
                    fb2[i] = *(const bf16x8*)&lsB2[rb2 * 64 + qb * 8];
                }
            }
            #pragma unroll
            for (int i = 0; i < 4; i++)
                #pragma unroll
                for (int j = 0; j < 4; j++) {
                    acc[i][j] = mfma16(fa[i], fb[j], acc[i][j]);
                    if (COMP) {
                        acc[i][j] = mfma16(fa[i], fb2[j], acc[i][j]);
                        acc[i][j] = mfma16(fa2[i], fb[j], acc[i][j]);
                    }
                }
        }
        __syncthreads();
    }

    // epilogue: C/D layout col = l&15, row = (l>>4)*4 + r  [m89/m91]
    #pragma unroll
    for (int i = 0; i < 4; i++) {
        #pragma unroll
        for (int j = 0; j < 4; j++) {
            #pragma unroll
            for (int r = 0; r < 4; r++) {
                const int mrow = m0 + wm + i * 16 + l4 * 4 + r;
                const int ncol = n0 + wn + j * 16 + l15;
                const float v = acc[i][j][r];
                if (EPI == 0) {
                    float* C = (float*)Cp + bz * sC;
                    const float mui = e0[bz * NF + mrow], muj = e0[bz * NF + ncol];
                    const float ii  = e1[bz * NF + mrow], ij  = e1[bz * NF + ncol];
                    C[(size_t)mrow * ldc + ncol] =
                        (v - (float)TSEQ * mui * muj) * ii * ij * (1.f / BATCH);
                } else if (EPI == 1) {
                    const size_t idx = (size_t)mrow * ldc + ncol;
                    const unsigned short hb = f2b(v);
                    ((unsigned short*)Cp)[idx]  = hb;
                    ((unsigned short*)Cp2)[idx] = f2b(v - b2f(hb));
                } else if (EPI == 2) {
                    const size_t idx = (size_t)mrow * ldc + ncol;
                    const float x0 = b2f(u0[idx]) + b2f(u1[idx]);
                    const float t1 = b2f(u2[idx]) + b2f(u3[idx]);
                    const float t2 = fminf(fmaxf(2.f * v - x0, -100.f), 100.f);
                    ((unsigned short*)Cp)[idx] = f2b(scal[0] * x0 + scal[1] * t1 + scal[2] * t2);
                } else if (EPI == 3) {
                    ((unsigned short*)Cp)[(size_t)mrow * ldc + ncol] = f2b(v + e0[ncol]);
                } else {
                    ((float*)Cp)[(size_t)mrow * ldc + ncol] = v + e0[ncol];
                }
            }
        }
    }
}

// ---------------------------------------------------------------------------
extern "C" void kernel_launch(void* const* d_in, const int* in_sizes, int n_in,
                              void* d_out, int out_size, void* d_ws, size_t ws_size,
                              hipStream_t stream)
{
    const float* x     = (const float*)d_in[0];
    const float* corr  = (const float*)d_in[1];
    const float* alpha = (const float*)d_in[2];
    const float* chw   = (const float*)d_in[3];
    const float* Wi    = (const float*)d_in[4];
    const float* bi    = (const float*)d_in[5];
    const float* Wo    = (const float*)d_in[6];
    const float* bo    = (const float*)d_in[7];
    const float* g1    = (const float*)d_in[8];
    const float* b1    = (const float*)d_in[9];
    const float* g2    = (const float*)d_in[10];
    const float* b2    = (const float*)d_in[11];
    const float* g3    = (const float*)d_in[12];
    const float* b3    = (const float*)d_in[13];
    float* out = (float*)d_out;

    // ws layout (MiB offsets). Overlays:
    //   0..128   hi(64)+lo(64)         -> hpre (bf16, 128)   -> ypre (f32, 128)
    //   128..256 hiT(64)+loT(64)       -> tx1hi(64)+tx1lo(64) -> hbuf (bf16, 128)
    //   256..320 chb (64)
    //   320..352 Smat (f32, 32)
    //   352+     small tensors
    char* wsb = (char*)d_ws;
    const size_t MB = 1024ull * 1024ull;
    unsigned short* hi    = (unsigned short*)(wsb + 0);
    unsigned short* lo    = (unsigned short*)(wsb + 64 * MB);
    unsigned short* hiT   = (unsigned short*)(wsb + 128 * MB);
    unsigned short* loT   = (unsigned short*)(wsb + 192 * MB);
    unsigned short* tx1hi = hiT;
    unsigned short* tx1lo = loT;
    unsigned short* chb   = (unsigned short*)(wsb + 256 * MB);
    unsigned short* hpre  = hi;                                // 128 MiB
    unsigned short* hbuf  = hiT;                               // 128 MiB
    float*          ypre  = (float*)(wsb + 0);                 // 128 MiB
    float* Smat   = (float*)(wsb + 320 * MB);                  // 32 MiB
    float* muv    = (float*)(wsb + 352 * MB);                  // 64 KiB
    float* invn   = (float*)(wsb + 352 * MB + 65536);          // 64 KiB
    float* mixedw = (float*)(wsb + 353 * MB);                  // 1 MiB
    float* disv   = (float*)(wsb + 354 * MB);                  // 2 KiB
    float* scal   = (float*)(wsb + 354 * MB + 4096);           // 16 B
    unsigned short* Lhi = (unsigned short*)(wsb + 355 * MB);   // 512 KiB
    unsigned short* Llo = (unsigned short*)(wsb + 355 * MB + 524288); // 512 KiB
    unsigned short* Wib = (unsigned short*)(wsb + 356 * MB);   // 1 MiB
    unsigned short* Wob = (unsigned short*)(wsb + 357 * MB);   // 1 MiB -> 358 MiB total

    const long NT2 = (long)NF * TSEQ;   // 1048576
    const long NN2 = (long)NF * NF;     // 262144

    scal_kernel<<<1, 1, 0, stream>>>(chw, alpha, scal);
    convw<<<2048, 256, 0, stream>>>(Wi, Wo, Wib, Wob);

    ln1<<<MROWS, 128, 0, stream>>>(x, hi, lo, g1, b1);
    transpose_bt<<<dim3(32, 8, 32), 256, 0, stream>>>(hi, hiT);
    transpose_bt<<<dim3(32, 8, 32), 256, 0, stream>>>(lo, loT);
    colstats_t<<<4096, 256, 0, stream>>>(hiT, loT, muv, invn);

    // Gram (compensated): per-batch normalized S, summed in mixed_kernel
    // grid 4x4x32 -> 512 blocks; swizzle gives each XCD 4 whole batches
    mgemm<0, true, 4, 4><<<512, 256, 0, stream>>>(
        hiT, hiT, loT, loT, Smat, nullptr, TSEQ, TSEQ, TSEQ, NF, NT2, NT2, NN2,
        muv, invn, nullptr, nullptr, nullptr, nullptr, nullptr);

    mixed_kernel<<<1024, 256, 0, stream>>>(Smat, corr, scal, mixedw,
                                           out + (long)MROWS * ODIM);
    deg_kernel<<<NF, 128, 0, stream>>>(mixedw, disv);
    lap_kernel<<<1024, 256, 0, stream>>>(mixedw, disv, Lhi, Llo);

    // Tx1 = xln @ L  (compensated, hi/lo split output)
    mgemm<1, true, 4, 512><<<2048, 256, 0, stream>>>(
        hi, Lhi, lo, Llo, tx1hi, tx1lo, NF, NF, NF, NF, 0, 0, 0,
        nullptr, nullptr, nullptr, nullptr, nullptr, nullptr, nullptr);
    // cheb_out = w0*x + w1*Tx1 + w2*clip(2*Tx1@L - x)  (compensated)
    mgemm<2, true, 4, 512><<<2048, 256, 0, stream>>>(
        tx1hi, Lhi, tx1lo, Llo, chb, nullptr, NF, NF, NF, NF, 0, 0, 0,
        nullptr, nullptr, hi, lo, tx1hi, tx1lo, scal);
    // hpre = cheb @ Wi^T + bi  (plain bf16)
    mgemm<3, false, 8, 512><<<4096, 256, 0, stream>>>(
        chb, Wib, nullptr, nullptr, hpre, nullptr, NF, NF, NF, HDIM, 0, 0, 0,
        bi, nullptr, nullptr, nullptr, nullptr, nullptr, nullptr);
    ln2g<<<MROWS, 256, 0, stream>>>(hpre, hbuf, g2, b2);
    // ypre = h @ Wo^T + bo  (plain bf16, f32 out)
    mgemm<4, false, 4, 512><<<2048, 256, 0, stream>>>(
        hbuf, Wob, nullptr, nullptr, ypre, nullptr, HDIM, HDIM, HDIM, ODIM, 0, 0, 0,
        bo, nullptr, nullptr, nullptr, nullptr, nullptr, nullptr);
    ln3<<<MROWS, 128, 0, stream>>>(ypre, out, g3, b3);
}